// Round 3
// baseline (95.714 us; speedup 1.0000x reference)
//
#include <hip/hip_runtime.h>
#include <stdint.h>

typedef __attribute__((ext_vector_type(8))) short short8;
typedef __attribute__((ext_vector_type(4))) float f32x4;

#define SEQ 256
#define NH 8

__device__ __forceinline__ uint32_t cvt_pk_bf16(float lo, float hi) {
  uint32_t r;
  asm("v_cvt_pk_bf16_f32 %0, %1, %2" : "=v"(r) : "v"(lo), "v"(hi));
  return r;
}

// ---------------------------------------------------------------------------
// Kernel 1: build layer-1 partial-sum tables (pre-ReLU), 4-way lane-split.
//   Apos[f][h][k]  = sum_p  e_pos[f,h,p]  * w1[p      ][k][h]   (f in [0,512))
//   Ai[b][m][h][k] = sum_j  e_bi[..]*w1[32+j][k][h] + e_ci[..]*w1[64+j][k][h]
//   Aj[b][n][h][k] = sum_j  e_bj[..]*w1[48+j][k][h] + e_cj[..]*w1[80+j][k][h]
// 4 adjacent lanes (sub=0..3) split the p/j sum, combine via shfl_xor(1,2).
// 655360 threads = 2560 blocks.
// ---------------------------------------------------------------------------
__global__ __launch_bounds__(256) void build_tables(
    const int* __restrict__ bseq, const int* __restrict__ cseq,
    const float* __restrict__ epos, const float* __restrict__ ebi,
    const float* __restrict__ ebj, const float* __restrict__ eci,
    const float* __restrict__ ecj, const float* __restrict__ w1,
    float* __restrict__ Apos, float* __restrict__ Ai, float* __restrict__ Aj) {
  int id = blockIdx.x * 256 + threadIdx.x;
  int sub = id & 3;
  int qid = id >> 2;
  f32x4 a = {0.f, 0.f, 0.f, 0.f};
  float* dst;
  if (qid < 32768) {                      // pos: 512*8*8 quads
    int kq = qid & 7, h = (qid >> 3) & 7, f = qid >> 6;
    const float* x = epos + (f * NH + h) * 32 + sub * 8;
    f32x4 x0 = *(const f32x4*)x;
    f32x4 x1 = *(const f32x4*)(x + 4);
    const float* wb = w1 + (sub * 8) * 256 + kq * 32 + h;
#pragma unroll
    for (int pi = 0; pi < 8; ++pi) {
      float xv = pi < 4 ? x0[pi & 3] : x1[pi & 3];
      const float* wr = wb + pi * 256;
      a[0] += xv * wr[0]; a[1] += xv * wr[8];
      a[2] += xv * wr[16]; a[3] += xv * wr[24];
    }
    dst = Apos + (f * NH + h) * 32 + kq * 4;
  } else {                                // i / j tables: 4*256*8*8 quads each
    int isI = (qid < 98304);
    int rid = qid - (isI ? 32768 : 98304);
    int kq = rid & 7, h = (rid >> 3) & 7, m = (rid >> 6) & 255, b = rid >> 14;
    int bidx = bseq[b * SEQ + m], cidx = cseq[b * SEQ + m];
    const float* xb = (isI ? ebi : ebj) + (bidx * NH + h) * 16 + sub * 4;
    const float* xc = (isI ? eci : ecj) + (cidx * NH + h) * 16 + sub * 4;
    f32x4 vb = *(const f32x4*)xb;
    f32x4 vc = *(const f32x4*)xc;
    const float* wbB = w1 + ((isI ? 32 : 48) + sub * 4) * 256 + kq * 32 + h;
    const float* wbC = w1 + ((isI ? 64 : 80) + sub * 4) * 256 + kq * 32 + h;
#pragma unroll
    for (int j = 0; j < 4; ++j) {
      float xv = vb[j];
      const float* wr = wbB + j * 256;
      a[0] += xv * wr[0]; a[1] += xv * wr[8];
      a[2] += xv * wr[16]; a[3] += xv * wr[24];
      float yv = vc[j];
      const float* wr2 = wbC + j * 256;
      a[0] += yv * wr2[0]; a[1] += yv * wr2[8];
      a[2] += yv * wr2[16]; a[3] += yv * wr2[24];
    }
    dst = (isI ? Ai : Aj) + ((b * SEQ + m) * NH + h) * 32 + kq * 4;
  }
  // combine sub-partials (lanes 4k..4k+3 share qid)
#pragma unroll
  for (int r = 0; r < 4; ++r) {
    a[r] += __shfl_xor(a[r], 1, 64);
    a[r] += __shfl_xor(a[r], 2, 64);
  }
  if (sub == 0) *(f32x4*)dst = a;
}

// ---------------------------------------------------------------------------
// Kernel 2: main. One wave = (b, h, 16 n, 16 m); 4 steps of 4 m-rows.
// Per m: e1-fragment (16 n, K=32) in bf16; mfma_f32_16x16x32_bf16 with
// A = w2^T (loop-invariant) gives D[l, n] = e2[n, l]; layer-3 = relu*w3
// dot + shfl_xor(16)+shfl_xor(32); lane (kb,lcol) stores cell
// (m_base+kb, ng*16+lcol) -> full-wave coalesced attn load + out store.
// ---------------------------------------------------------------------------
__global__ __launch_bounds__(256, 4) void dis_att_main(
    const float* __restrict__ attn, const float* __restrict__ w2,
    const float* __restrict__ w3, const float* __restrict__ Apos,
    const float* __restrict__ Ai, const float* __restrict__ Aj,
    float* __restrict__ out) {
  int lane = threadIdx.x & 63;
  int wid = blockIdx.x * 4 + (threadIdx.x >> 6);   // 0..8191
  int mo = wid & 15, ng = (wid >> 4) & 15, h = (wid >> 8) & 7, b = wid >> 11;
  int lcol = lane & 15, kb = lane >> 4, k8 = kb * 8;
  int n = ng * 16 + lcol;

  // Aj contribution: fixed per lane
  const float* ajp = Aj + ((b * SEQ + n) * NH + h) * 32 + k8;
  f32x4 aj0 = *(const f32x4*)ajp;
  f32x4 aj1 = *(const f32x4*)(ajp + 4);

  // A-fragment = w2^T : A[i,k] = w2[k][i][h], lane row i = lcol, k = k8..k8+7
  union { uint32_t u[4]; short8 v; } w2f;
#pragma unroll
  for (int r = 0; r < 4; ++r) {
    float lo = w2[(k8 + 2 * r) * 128 + lcol * 8 + h];
    float hi = w2[(k8 + 2 * r + 1) * 128 + lcol * 8 + h];
    w2f.u[r] = cvt_pk_bf16(lo, hi);
  }
  float w3v[4];
#pragma unroll
  for (int r = 0; r < 4; ++r) w3v[r] = w3[(k8 / 2 + r) * 8 + h];

  const float* aib = Ai + (b * SEQ * NH + h) * 32 + k8;          // + m*256
  const float* apb = Apos + (256 - n) * (NH * 32) + h * 32 + k8; // + m*256

  for (int s = 0; s < 4; ++s) {
    int m_base = mo * 16 + s * 4;
    // full-wave coalesced attn load: lane (kb,lcol) -> row m_base+kb, col n
    int idx = ((b * NH + h) * SEQ + (m_base + kb)) * SEQ + ng * 16 + lcol;
    float av = attn[idx];

    float part[4];
#pragma unroll
    for (int mi = 0; mi < 4; ++mi) {
      int m = m_base + mi;
      const float* ap = apb + m * (NH * 32);
      f32x4 p0 = *(const f32x4*)ap;
      f32x4 p1 = *(const f32x4*)(ap + 4);
      const float* ai = aib + m * (NH * 32);
      f32x4 i0 = *(const f32x4*)ai;
      f32x4 i1 = *(const f32x4*)(ai + 4);
      f32x4 s0 = p0 + i0 + aj0;
      f32x4 s1 = p1 + i1 + aj1;
      union { uint32_t u[4]; short8 v; } ef;
      ef.u[0] = cvt_pk_bf16(fmaxf(s0[0], 0.f), fmaxf(s0[1], 0.f));
      ef.u[1] = cvt_pk_bf16(fmaxf(s0[2], 0.f), fmaxf(s0[3], 0.f));
      ef.u[2] = cvt_pk_bf16(fmaxf(s1[0], 0.f), fmaxf(s1[1], 0.f));
      ef.u[3] = cvt_pk_bf16(fmaxf(s1[2], 0.f), fmaxf(s1[3], 0.f));
      f32x4 c = {0.f, 0.f, 0.f, 0.f};
      f32x4 d = __builtin_amdgcn_mfma_f32_16x16x32_bf16(w2f.v, ef.v, c, 0, 0, 0);
      part[mi] = fmaxf(d[0], 0.f) * w3v[0] + fmaxf(d[1], 0.f) * w3v[1] +
                 fmaxf(d[2], 0.f) * w3v[2] + fmaxf(d[3], 0.f) * w3v[3];
      part[mi] += __shfl_xor(part[mi], 16, 64);
      part[mi] += __shfl_xor(part[mi], 32, 64);
    }
    // lane needs part[kb] (its own m-row), same n
    float p01 = (kb & 1) ? part[1] : part[0];
    float p23 = (kb & 1) ? part[3] : part[2];
    float pf = (kb & 2) ? p23 : p01;
    out[idx] = av + pf;
  }
}

extern "C" void kernel_launch(void* const* d_in, const int* in_sizes, int n_in,
                              void* d_out, int out_size, void* d_ws, size_t ws_size,
                              hipStream_t stream) {
  const float* attn = (const float*)d_in[0];
  const int* bseq   = (const int*)d_in[1];
  const int* cseq   = (const int*)d_in[2];
  const float* epos = (const float*)d_in[3];
  const float* ebi  = (const float*)d_in[4];
  const float* ebj  = (const float*)d_in[5];
  const float* eci  = (const float*)d_in[6];
  const float* ecj  = (const float*)d_in[7];
  const float* w1   = (const float*)d_in[8];
  const float* w2   = (const float*)d_in[9];
  const float* w3   = (const float*)d_in[10];
  float* out = (float*)d_out;

  float* Apos = (float*)d_ws;            // 512*8*32   = 131072 f32 (512 KB)
  float* Ai   = Apos + 131072;           // 4*256*8*32 = 262144 f32 (1 MB)
  float* Aj   = Ai + 262144;             // 262144 f32 (1 MB)

  hipLaunchKernelGGL(build_tables, dim3(2560), dim3(256), 0, stream,
                     bseq, cseq, epos, ebi, ebj, eci, ecj, w1, Apos, Ai, Aj);
  hipLaunchKernelGGL(dis_att_main, dim3(2048), dim3(256), 0, stream,
                     attn, w2, w3, Apos, Ai, Aj, out);
}

// Round 5
// 28.662 us; speedup vs baseline: 3.3394x; 3.3394x over previous
//
#include <hip/hip_runtime.h>
#include <stdint.h>

typedef __attribute__((ext_vector_type(8))) short short8;
typedef __attribute__((ext_vector_type(4))) float f32x4;

#define SEQ 256
#define NH 8

__device__ __forceinline__ uint32_t cvt_pk_bf16(float lo, float hi) {
  uint32_t r;
  asm("v_cvt_pk_bf16_f32 %0, %1, %2" : "=v"(r) : "v"(lo), "v"(hi));
  return r;
}

__device__ __forceinline__ short8 pack8(f32x4 a, f32x4 b) {
  union { uint32_t u[4]; short8 v; } t;
  t.u[0] = cvt_pk_bf16(a[0], a[1]);
  t.u[1] = cvt_pk_bf16(a[2], a[3]);
  t.u[2] = cvt_pk_bf16(b[0], b[1]);
  t.u[3] = cvt_pk_bf16(b[2], b[3]);
  return t.v;
}

// ---------------------------------------------------------------------------
// ONE fused kernel. Block = (b, h, 64m x 64n) tile, 512 thr (8 waves).
// Phase 1: build pre-ReLU layer-1 tables IN-BLOCK via MFMA:
//   sAp[rl][k] (rl=local m-n+63, 128 rows, row127 junk) = E_pos * W_pos
//   sAi[lm][k] = [ebi|eci](gathered) * W_i ;  sAj[ln][k] = [ebj|ecj] * W_j
//   (A-frag: row=lane&15, k=kb*8+j; B-frag: col=lane&15, k=kb*8+j;
//    D: col=lane&15, row=kb*4+reg -- same conventions as phase 2, validated)
// Phase 2: per m: e1=relu(Ap+Ai+Aj) -> bf16; mfma(A=w2^T) -> e2^T;
//   layer-3 relu-dot + shfl_xor(16,32); coalesced attn-add store.
// No workspace, no cross-kernel deps: replay-proof.
// ---------------------------------------------------------------------------
__global__ __launch_bounds__(512, 2) void dis_att_fused(
    const float* __restrict__ attn, const int* __restrict__ bseq,
    const int* __restrict__ cseq, const float* __restrict__ epos,
    const float* __restrict__ ebi, const float* __restrict__ ebj,
    const float* __restrict__ eci, const float* __restrict__ ecj,
    const float* __restrict__ w1, const float* __restrict__ w2,
    const float* __restrict__ w3, float* __restrict__ out) {
  __shared__ float sAp[128][36];
  __shared__ float sAi[64][36];
  __shared__ float sAj[64][36];
  int tid = threadIdx.x;
  int wg = blockIdx.x;                     // 512 = b(4) h(8) mt(4) nt(4)
  int nt = wg & 3, mt = (wg >> 2) & 3, h = (wg >> 4) & 7, b = wg >> 7;
  int m0 = mt * 64, n0 = nt * 64;
  int f0 = m0 - n0 + 193;                  // global f of sAp row 0
  int lane = tid & 63, w = tid >> 6;
  int lcol = lane & 15, kb = lane >> 4, k8 = kb * 8;
  f32x4 zero = {0.f, 0.f, 0.f, 0.f};

  // ---------------- phase 1: build tables ----------------
  if (w < 4) {                             // Apos band: m-tiles {w, w+4} x kk{0,1}
    short8 bf[2];
#pragma unroll
    for (int kt = 0; kt < 2; ++kt) {       // B = W_pos[k=p][kk]
      union { uint32_t u[4]; short8 v; } t;
#pragma unroll
      for (int r = 0; r < 4; ++r) {
        float lo = w1[(k8 + 2 * r) * 256 + (kt * 16 + lcol) * 8 + h];
        float hi = w1[(k8 + 2 * r + 1) * 256 + (kt * 16 + lcol) * 8 + h];
        t.u[r] = cvt_pk_bf16(lo, hi);
      }
      bf[kt] = t.v;
    }
#pragma unroll
    for (int t = 0; t < 2; ++t) {
      int mt_ = w + t * 4;                 // tile 0..7 (rows mt_*16..+15)
      int frow = f0 + mt_ * 16 + lcol;
      if (frow > 511) frow = 511;          // row 127 junk, never read
      const float* ep = epos + (frow * NH + h) * 32 + k8;
      short8 af = pack8(*(const f32x4*)ep, *(const f32x4*)(ep + 4));
#pragma unroll
      for (int kt = 0; kt < 2; ++kt) {
        f32x4 d = __builtin_amdgcn_mfma_f32_16x16x32_bf16(af, bf[kt], zero, 0, 0, 0);
#pragma unroll
        for (int r = 0; r < 4; ++r)
          sAp[mt_ * 16 + kb * 4 + r][kt * 16 + lcol] = d[r];
      }
    }
  } else {                                 // Ai (waves 4,5) / Aj (waves 6,7)
    int isI = w < 6;
    int p0 = isI ? ((kb < 2 ? 32 : 48) + k8)    // W_i rows: 32..47 | 64..79
                 : ((kb < 2 ? 48 : 64) + k8);   // W_j rows: 48..63 | 80..95
    short8 bf[2];
#pragma unroll
    for (int kt = 0; kt < 2; ++kt) {
      union { uint32_t u[4]; short8 v; } t;
#pragma unroll
      for (int r = 0; r < 4; ++r) {
        float lo = w1[(p0 + 2 * r) * 256 + (kt * 16 + lcol) * 8 + h];
        float hi = w1[(p0 + 2 * r + 1) * 256 + (kt * 16 + lcol) * 8 + h];
        t.u[r] = cvt_pk_bf16(lo, hi);
      }
      bf[kt] = t.v;
    }
    const float* eB = isI ? ebi : ebj;
    const float* eC = isI ? eci : ecj;
    int base = isI ? m0 : n0;
    int w2_ = isI ? (w - 4) : (w - 6);
#pragma unroll
    for (int t = 0; t < 2; ++t) {
      int mt_ = w2_ * 2 + t;               // tile 0..3 (rows mt_*16..+15)
      int gm = b * SEQ + base + mt_ * 16 + lcol;
      int bi = bseq[gm], ci = cseq[gm];
      const float* src = (kb < 2) ? eB + (bi * NH + h) * 16 + k8
                                  : eC + (ci * NH + h) * 16 + (k8 - 16);
      short8 af = pack8(*(const f32x4*)src, *(const f32x4*)(src + 4));
#pragma unroll
      for (int kt = 0; kt < 2; ++kt) {
        f32x4 d = __builtin_amdgcn_mfma_f32_16x16x32_bf16(af, bf[kt], zero, 0, 0, 0);
#pragma unroll
        for (int r = 0; r < 4; ++r) {
          float* T = isI ? &sAi[mt_ * 16 + kb * 4 + r][kt * 16 + lcol]
                         : &sAj[mt_ * 16 + kb * 4 + r][kt * 16 + lcol];
          *T = d[r];
        }
      }
    }
  }
  __syncthreads();

  // ---------------- phase 2: main compute ----------------
  union { uint32_t u[4]; short8 v; } w2f;  // A = w2^T: row=lcol, k=k8..k8+7
#pragma unroll
  for (int r = 0; r < 4; ++r) {
    float lo = w2[(k8 + 2 * r) * 128 + lcol * 8 + h];
    float hi = w2[(k8 + 2 * r + 1) * 128 + lcol * 8 + h];
    w2f.u[r] = cvt_pk_bf16(lo, hi);
  }
  float w3v[4];
#pragma unroll
  for (int r = 0; r < 4; ++r) w3v[r] = w3[(kb * 4 + r) * 8 + h];

  const float* attn_b = attn + (b * NH + h) * SEQ * SEQ;
  float* out_b = out + (b * NH + h) * SEQ * SEQ;

#pragma unroll
  for (int s = 0; s < 2; ++s) {
    int mb = w * 8 + s * 4;
    float av[4];
    int idxs[4];
#pragma unroll
    for (int ng = 0; ng < 4; ++ng) {
      idxs[ng] = (m0 + mb + kb) * SEQ + n0 + ng * 16 + lcol;
      av[ng] = attn_b[idxs[ng]];
    }
    f32x4 ai0[4], ai1[4];
#pragma unroll
    for (int mi = 0; mi < 4; ++mi) {
      ai0[mi] = *(const f32x4*)&sAi[mb + mi][k8];
      ai1[mi] = *(const f32x4*)&sAi[mb + mi][k8 + 4];
    }
#pragma unroll
    for (int ng = 0; ng < 4; ++ng) {
      int nl = ng * 16 + lcol;
      f32x4 aj0 = *(const f32x4*)&sAj[nl][k8];
      f32x4 aj1 = *(const f32x4*)&sAj[nl][k8 + 4];
      float part[4];
#pragma unroll
      for (int mi = 0; mi < 4; ++mi) {
        int rl = mb + mi - nl + 63;
        f32x4 p0 = *(const f32x4*)&sAp[rl][k8];
        f32x4 p1 = *(const f32x4*)&sAp[rl][k8 + 4];
        f32x4 s0 = p0 + ai0[mi] + aj0;
        f32x4 s1 = p1 + ai1[mi] + aj1;
        union { uint32_t u[4]; short8 v; } ef;
        ef.u[0] = cvt_pk_bf16(fmaxf(s0[0], 0.f), fmaxf(s0[1], 0.f));
        ef.u[1] = cvt_pk_bf16(fmaxf(s0[2], 0.f), fmaxf(s0[3], 0.f));
        ef.u[2] = cvt_pk_bf16(fmaxf(s1[0], 0.f), fmaxf(s1[1], 0.f));
        ef.u[3] = cvt_pk_bf16(fmaxf(s1[2], 0.f), fmaxf(s1[3], 0.f));
        f32x4 d = __builtin_amdgcn_mfma_f32_16x16x32_bf16(w2f.v, ef.v, zero, 0, 0, 0);
        float p = fmaxf(d[0], 0.f) * w3v[0] + fmaxf(d[1], 0.f) * w3v[1] +
                  fmaxf(d[2], 0.f) * w3v[2] + fmaxf(d[3], 0.f) * w3v[3];
        p += __shfl_xor(p, 16, 64);
        p += __shfl_xor(p, 32, 64);
        part[mi] = p;
      }
      float p01 = (kb & 1) ? part[1] : part[0];
      float p23 = (kb & 1) ? part[3] : part[2];
      float pf = (kb & 2) ? p23 : p01;
      out_b[idxs[ng]] = av[ng] + pf;
    }
  }
}

extern "C" void kernel_launch(void* const* d_in, const int* in_sizes, int n_in,
                              void* d_out, int out_size, void* d_ws, size_t ws_size,
                              hipStream_t stream) {
  const float* attn = (const float*)d_in[0];
  const int* bseq   = (const int*)d_in[1];
  const int* cseq   = (const int*)d_in[2];
  const float* epos = (const float*)d_in[3];
  const float* ebi  = (const float*)d_in[4];
  const float* ebj  = (const float*)d_in[5];
  const float* eci  = (const float*)d_in[6];
  const float* ecj  = (const float*)d_in[7];
  const float* w1   = (const float*)d_in[8];
  const float* w2   = (const float*)d_in[9];
  const float* w3   = (const float*)d_in[10];
  float* out = (float*)d_out;

  hipLaunchKernelGGL(dis_att_fused, dim3(512), dim3(512), 0, stream,
                     attn, bseq, cseq, epos, ebi, ebj, eci, ecj, w1, w2, w3, out);
}